// Round 5
// baseline (324.817 us; speedup 1.0000x reference)
//
#include <hip/hip_runtime.h>
#include <hip/hip_bf16.h>

// f32-uniform output buffer: final_out [B,512] (bf16-rounded f32),
// guide_loss f32 @ B*512, sel_emb [B,128] f32 @ B*512+1.
// B=16384, E=8, D_IN=900, D_MODEL=512, D_SEL=128, top-2.

#define B_ROWS 16384
#define DIN 900
#define DM 512
#define DSEL 128
#define KP 928
#define NKS 29
#define MAXT 192
#define EPSF 1e-9f

#define OUT_GUIDE (B_ROWS*DM)
#define OUT_SEL   (B_ROWS*DM + 1)

// workspace layout (bytes); total ~8.4 MB (proven footprint)
#define WS_COUNTS 0                      // int[64]
#define WS_PART   512                    // float[64]
#define WS_NT     768                    // int
#define WS_OFF    1024                   // int[64]
#define WS_ENT    2048                   // int4[448]
#define WS_BB     9216                   // int[64*64] block bases
#define WS_PIDLR  25600                  // int[B]  pid | (lrank<<8)
#define WS_GATEB  91136                  // float2[B]
#define WS_W8     222208                 // float[B*8] inactive-mixture weights
#define WS_ROWSS  746496                 // int[B]
#define WS_WT     812032                 // ushort[E*32*29*512] frag-tiled W (7.6 MB)

#define FRSTRIDE 14848                   // 29*512: wt2 stride between col-groups

typedef __attribute__((ext_vector_type(8))) short short8;
typedef __attribute__((ext_vector_type(8))) unsigned short ushort8;
typedef __attribute__((ext_vector_type(4))) float floatx4;

__device__ inline unsigned short f2bf(float v){
  union { __hip_bfloat16 h; unsigned short u; } c;
  c.h = __float2bfloat16(v);
  return c.u;
}
__device__ inline float bf2f(unsigned short u){
  union { unsigned int i; float f; } c;
  c.i = ((unsigned int)u) << 16;
  return c.f;
}
__device__ inline ushort8 pack8u(float4 a, float4 b){
  ushort8 c;
  c[0]=f2bf(a.x); c[1]=f2bf(a.y); c[2]=f2bf(a.z); c[3]=f2bf(a.w);
  c[4]=f2bf(b.x); c[5]=f2bf(b.y); c[6]=f2bf(b.z); c[7]=f2bf(b.w);
  return c;
}

// ---- W f32 [E,900,512] -> bf16 fragment tiles wt2[e][ncg][kc][col16][kk32] ----
// element (e, n=ncg*16+col, k=kc*32+kk) at ((e*32+ncg)*29+kc)*512 + col*32 + kk
__global__ __launch_bounds__(256) void cvtw2_k(const float* __restrict__ W,
                                               unsigned short* __restrict__ wt2){
  __shared__ unsigned short lds[32][512];
  int t = threadIdx.x;
  int kc = blockIdx.x, e = blockIdx.y;
  for (int kk = 0; kk < 32; ++kk){
    int k = kc*32 + kk;
    if (k < DIN){
      const float* wr = W + ((size_t)e*DIN + k)*DM;
      lds[kk][t]       = f2bf(wr[t]);
      lds[kk][t + 256] = f2bf(wr[t + 256]);
    } else {
      lds[kk][t] = 0; lds[kk][t + 256] = 0;
    }
  }
  __syncthreads();
  int ncg = t >> 3, q = t & 7;
  unsigned short* ob = wt2 + (((size_t)e*32 + ncg)*29 + kc)*512;
  for (int i = 0; i < 8; ++i){
    int fb = i*64 + q*8;          // ushort offset within this frag-tile
    int col = fb >> 5, kk0 = fb & 31;
    ushort8 y;
    #pragma unroll
    for (int j = 0; j < 8; ++j) y[j] = lds[kk0 + j][ncg*16 + col];
    *((ushort8*)(ob + fb)) = y;
  }
}

// ---- gating: thread-per-row; no hot atomics ----
__global__ __launch_bounds__(256) void gating_k(const float* __restrict__ logits,
                                                const int* __restrict__ masks,
                                                int* __restrict__ counts,
                                                float* __restrict__ partials,
                                                int* __restrict__ pidlr,
                                                float2* __restrict__ gatesb,
                                                float* __restrict__ w8,
                                                int* __restrict__ blockbase){
  __shared__ int hist[64];
  __shared__ float wsum[4];
  int t = threadIdx.x;
  if (t < 64) hist[t] = 0;
  __syncthreads();
  int b = blockIdx.x*256 + t;
  float4 l0 = *(const float4*)&logits[(size_t)b*8];
  float4 l1 = *(const float4*)&logits[(size_t)b*8 + 4];
  int4  m0 = *(const int4*)&masks[(size_t)b*8];
  int4  m1 = *(const int4*)&masks[(size_t)b*8 + 4];
  float raw[8] = {l0.x,l0.y,l0.z,l0.w,l1.x,l1.y,l1.z,l1.w};
  int   mk[8]  = {m0.x,m0.y,m0.z,m0.w,m1.x,m1.y,m1.z,m1.w};
  float mx = raw[0];
  for (int e = 1; e < 8; e++) mx = fmaxf(mx, raw[e]);
  float Z = 0.f;
  for (int e = 0; e < 8; e++){ raw[e] = expf(raw[e]-mx); Z += raw[e]; }
  float invZ = 1.f/Z;
  float act[8], ina[8]; float srm = 0.f, isum = 0.f;
  for (int e = 0; e < 8; e++){
    raw[e] *= invZ;
    if (mk[e] == 1){ act[e] = raw[e]; ina[e] = 0.f; srm += raw[e]; }
    else           { act[e] = 0.f;    ina[e] = raw[e]; isum += raw[e]; }
  }
  float v1 = -1.f, v2 = -1.f; int e1 = 0, e2 = 0;
  for (int e = 0; e < 8; e++){
    float a = act[e];
    if (a > v1){ v2 = v1; e2 = e1; v1 = a; e1 = e; }
    else if (a > v2){ v2 = a; e2 = e; }
  }
  float den = v1 + v2 + EPSF;
  float g1 = v1/den, g2 = v2/den;
  int lo, hi; float gl, gh;
  if (e1 < e2){ lo = e1; hi = e2; gl = g1; gh = g2; }
  else        { lo = e2; hi = e1; gl = g2; gh = g1; }
  int pid = lo*8 + hi;
  float invI = 1.f/(isum + EPSF);
  for (int e = 0; e < 8; e++) w8[(size_t)b*8 + e] = ina[e]*invI;
  gatesb[b] = make_float2(gl, gh);
  int lr = atomicAdd(&hist[pid], 1);     // LDS atomic: local rank
  pidlr[b] = pid | (lr << 8);
  // block reduce srm -> partials[blockIdx]
  float s = srm;
  for (int sft = 32; sft > 0; sft >>= 1) s += __shfl_down(s, sft, 64);
  if ((t & 63) == 0) wsum[t >> 6] = s;
  __syncthreads();
  if (t < 64){
    int c = hist[t];
    int base = 0;
    if (c > 0) base = atomicAdd(&counts[t], c);   // <=64 atomics/block
    blockbase[blockIdx.x*64 + t] = base;
  }
  if (t == 0) partials[blockIdx.x] = wsum[0] + wsum[1] + wsum[2] + wsum[3];
}

// ---- selection embedding (+ fused scatter): coalesced, 2 rows per block ----
__global__ __launch_bounds__(256) void selemb_k(const float* __restrict__ sel,
                                                const float* __restrict__ w8,
                                                const int* __restrict__ pidlr,
                                                const int* __restrict__ off,
                                                const int* __restrict__ blockbase,
                                                int* __restrict__ rows_s,
                                                float* __restrict__ out){
  int t = threadIdx.x;
  int b = blockIdx.x*2 + (t >> 7);
  int d = t & 127;
  if (d == 0){
    int pl = pidlr[b];
    int p = pl & 63;
    int lr = pl >> 8;
    rows_s[off[p] + blockbase[(b >> 8)*64 + p] + lr] = b;
  }
  const float* wr = w8 + (size_t)b*8;
  const float* sb = sel + (size_t)b*(8*DSEL);
  float a = 0.f;
  for (int e = 0; e < 8; e++) a += wr[e] * sb[e*DSEL + d];
  out[OUT_SEL + (size_t)b*DSEL + d] = a;
}

// ---- worklist: one 64-lane wave; shuffle scans; guide loss ----
__global__ void worklist_k(const int* __restrict__ counts,
                           const float* __restrict__ partials,
                           int* __restrict__ off, int* __restrict__ ntp,
                           int4* __restrict__ entries,
                           float* __restrict__ out){
  int lane = threadIdx.x;      // 64 threads
  int c = counts[lane];
  int sc = c;
  for (int s = 1; s < 64; s <<= 1){ int v = __shfl_up(sc, s, 64); if (lane >= s) sc += v; }
  int offp = sc - c;
  off[lane] = offp;
  int nt = (c + 127) >> 7;
  int snt = nt;
  for (int s = 1; s < 64; s <<= 1){ int v = __shfl_up(snt, s, 64); if (lane >= s) snt += v; }
  int tbase = snt - nt;
  int elo = lane >> 3, ehi = lane & 7;
  for (int j = 0; j < nt; ++j){
    int nr = c - j*128; if (nr > 128) nr = 128;
    entries[tbase + j] = make_int4(elo, ehi, offp + j*128, nr);
  }
  int tot = __shfl(snt, 63, 64);
  if (lane == 0) *ntp = tot;
  float p = partials[lane];
  for (int s = 32; s > 0; s >>= 1) p += __shfl_down(p, s, 64);
  if (lane == 0){
    float sv = p * (1.f/B_ROWS);
    float d = 1.f - sv;
    out[OUT_GUIDE] = d*d;
  }
}

// ---- grouped GEMM v5: A staged in LDS (pad-36, conflict-free, dbuf,
//      depth-2 register prefetch, ONE barrier/K-step); B streamed per-wave
//      from frag-tiled wt2 (contiguous, prefetched, flies across barriers);
//      XCD swizzle co-locates a tile's 4 col-blocks on one XCD L2. ----

#define ALOADV(P, kk) { \
  const float4* p_ = (const float4*)(xrow + (kk)*32); \
  P##0 = p_[0]; P##1 = p_[1]; P##2 = p_[2]; P##3 = p_[3]; }

#define ALOADT(P) { \
  float tmp[16]; \
  _Pragma("unroll") \
  for (int j = 0; j < 16; ++j){ \
    int k = 896 + skc*16 + j; \
    tmp[j] = (k < DIN) ? xrow[28*32 + j] : 0.f; \
  } \
  P##0 = make_float4(tmp[0],tmp[1],tmp[2],tmp[3]); \
  P##1 = make_float4(tmp[4],tmp[5],tmp[6],tmp[7]); \
  P##2 = make_float4(tmp[8],tmp[9],tmp[10],tmp[11]); \
  P##3 = make_float4(tmp[12],tmp[13],tmp[14],tmp[15]); }

#define AWR(buf, P) { \
  *((ushort8*)&as_[buf][srow*36 + skc*16])     = pack8u(P##0, P##1); \
  *((ushort8*)&as_[buf][srow*36 + skc*16 + 8]) = pack8u(P##2, P##3); }

#define MFJ(j) { \
  acc[0][0][j] = __builtin_amdgcn_mfma_f32_16x16x32_bf16(af0, b0c, acc[0][0][j], 0, 0, 0); \
  acc[0][1][j] = __builtin_amdgcn_mfma_f32_16x16x32_bf16(af1, b0c, acc[0][1][j], 0, 0, 0); \
  acc[0][2][j] = __builtin_amdgcn_mfma_f32_16x16x32_bf16(af2, b0c, acc[0][2][j], 0, 0, 0); \
  acc[0][3][j] = __builtin_amdgcn_mfma_f32_16x16x32_bf16(af3, b0c, acc[0][3][j], 0, 0, 0); \
  acc[1][0][j] = __builtin_amdgcn_mfma_f32_16x16x32_bf16(af0, b1c, acc[1][0][j], 0, 0, 0); \
  acc[1][1][j] = __builtin_amdgcn_mfma_f32_16x16x32_bf16(af1, b1c, acc[1][1][j], 0, 0, 0); \
  acc[1][2][j] = __builtin_amdgcn_mfma_f32_16x16x32_bf16(af2, b1c, acc[1][2][j], 0, 0, 0); \
  acc[1][3][j] = __builtin_amdgcn_mfma_f32_16x16x32_bf16(af3, b1c, acc[1][3][j], 0, 0, 0); }

#define KSTEP(ks, cur, LAST) { \
  short8 af0 = *((const short8*)&as_[cur][(wrow*64 +  0 + l16)*36 + quad*8]); \
  short8 af1 = *((const short8*)&as_[cur][(wrow*64 + 16 + l16)*36 + quad*8]); \
  short8 af2 = *((const short8*)&as_[cur][(wrow*64 + 32 + l16)*36 + quad*8]); \
  short8 af3 = *((const short8*)&as_[cur][(wrow*64 + 48 + l16)*36 + quad*8]); \
  short8 b0n, b1n; \
  b0n = *((const short8*)(bp0 + 1*FRSTRIDE + (size_t)(ks)*512)); \
  b1n = *((const short8*)(bp1 + 1*FRSTRIDE + (size_t)(ks)*512)); \
  MFJ(0); b0c = b0n; b1c = b1n; \
  b0n = *((const short8*)(bp0 + 2*FRSTRIDE + (size_t)(ks)*512)); \
  b1n = *((const short8*)(bp1 + 2*FRSTRIDE + (size_t)(ks)*512)); \
  MFJ(1); b0c = b0n; b1c = b1n; \
  b0n = *((const short8*)(bp0 + 3*FRSTRIDE + (size_t)(ks)*512)); \
  b1n = *((const short8*)(bp1 + 3*FRSTRIDE + (size_t)(ks)*512)); \
  MFJ(2); b0c = b0n; b1c = b1n; \
  if (!(LAST)){ \
    b0n = *((const short8*)(bp0 + (size_t)((ks)+1)*512)); \
    b1n = *((const short8*)(bp1 + (size_t)((ks)+1)*512)); \
  } \
  MFJ(3); b0c = b0n; b1c = b1n; }

__global__ __launch_bounds__(256, 2) void gemm_k(const float* __restrict__ xf,
                                                 const unsigned short* __restrict__ wt2,
                                                 const float* __restrict__ bias,
                                                 const int* __restrict__ ntp,
                                                 const int4* __restrict__ entries,
                                                 const int* __restrict__ rows_s,
                                                 const float2* __restrict__ gatesb,
                                                 float* __restrict__ out){
  // XCD swizzle: 4 col-blocks of a tile share id%8 -> same XCD (L2 reuse of x rows)
  int id = blockIdx.x;
  int tile = (id >> 5)*8 + (id & 7);
  int y = (id >> 3) & 3;
  if (tile >= *ntp) return;
  int4 ent = entries[tile];
  int elo = ent.x, ehi = ent.y, start = ent.z, nrows = ent.w;

  __shared__ __align__(16) unsigned short as_[2][128*36];   // A bf16, 72B rows (conflict-free)
  __shared__ int   gidx_s[128];
  __shared__ float glo_s[128];
  __shared__ float ghi_s[128];

  int t = threadIdx.x;
  if (t < 128){
    if (t < nrows){
      int g = rows_s[start + t];
      gidx_s[t] = g;
      float2 gg = gatesb[g];
      glo_s[t] = gg.x; ghi_s[t] = gg.y;
    } else { gidx_s[t] = -1; glo_s[t] = 0.f; ghi_s[t] = 0.f; }
  }
  __syncthreads();

  int lane = t & 63, wid = t >> 6;
  int wrow = wid >> 1, wcol = wid & 1;
  int quad = lane >> 4, l16 = lane & 15;
  int ncg0 = y*8 + wcol*4;

  // A staging mapping: thread t stages row t>>1, half (t&1)*16 of each 32-k chunk
  int srow = t >> 1, skc = t & 1;
  int sg = gidx_s[srow];
  const float* xrow = xf + (size_t)(sg >= 0 ? sg : 0)*DIN + skc*16;

  // B stream pointers (per-wave contiguous 1KB frag tiles)
  const unsigned short* bp0 = wt2 + ((size_t)(elo*32 + ncg0))*FRSTRIDE + l16*32 + quad*8;
  const unsigned short* bp1 = wt2 + ((size_t)(ehi*32 + ncg0))*FRSTRIDE + l16*32 + quad*8;

  floatx4 acc[2][4][4];
  #pragma unroll
  for (int i = 0; i < 2; i++)
    #pragma unroll
    for (int j = 0; j < 4; j++)
      #pragma unroll
      for (int k = 0; k < 4; k++)
        #pragma unroll
        for (int r = 0; r < 4; r++) acc[i][j][k][r] = 0.f;

  float4 rE0, rE1, rE2, rE3;   // A raw regs, even steps
  float4 rO0, rO1, rO2, rO3;   // A raw regs, odd steps

  ALOADV(rE, 0);
  ALOADV(rO, 1);
  AWR(0, rE);
  short8 b0c = *((const short8*)(bp0));
  short8 b1c = *((const short8*)(bp1));
  __syncthreads();

  for (int ks = 0; ks < 28; ks += 2){
    // even step: compute ks from buf0; issue A(ks+2); write buf1 <- A(ks+1)
    if (ks < 26){ ALOADV(rE, ks+2); } else { ALOADT(rE); }
    KSTEP(ks, 0, false);
    AWR(1, rO);
    __syncthreads();
    // odd step: compute ks+1 from buf1; issue A(ks+3); write buf0 <- A(ks+2)
    if (ks < 26){ ALOADV(rO, ks+3); }
    KSTEP(ks+1, 1, false);
    AWR(0, rE);
    __syncthreads();
  }
  KSTEP(28, 0, true);

  // epilogue: gates + bias in f32 (== ref's g*(xW+b) summed over top-2)
  int colbase = y*128 + wcol*64;
  float blo[4], bhi[4];
  #pragma unroll
  for (int nt = 0; nt < 4; ++nt){
    int n = colbase + nt*16 + l16;
    blo[nt] = bias[elo*DM + n];
    bhi[nt] = bias[ehi*DM + n];
  }
  #pragma unroll
  for (int mt = 0; mt < 4; ++mt){
    #pragma unroll
    for (int r = 0; r < 4; ++r){
      int rr = wrow*64 + mt*16 + quad*4 + r;
      int grow = gidx_s[rr];
      if (grow >= 0){
        float2 gg = gatesb[grow];
        float* orow = out + (size_t)grow*DM;
        #pragma unroll
        for (int nt = 0; nt < 4; ++nt){
          int n = colbase + nt*16 + l16;
          float v = gg.x*(acc[0][mt][nt][r] + blo[nt]) + gg.y*(acc[1][mt][nt][r] + bhi[nt]);
          orow[n] = bf2f(f2bf(v));
        }
      }
    }
  }
}

extern "C" void kernel_launch(void* const* d_in, const int* in_sizes, int n_in,
                              void* d_out, int out_size, void* d_ws, size_t ws_size,
                              hipStream_t stream){
  const float* x      = (const float*)d_in[0];
  const float* logits = (const float*)d_in[1];
  const int*   masks  = (const int*)d_in[2];
  const float* sel    = (const float*)d_in[3];
  const float* W      = (const float*)d_in[4];
  const float* bias   = (const float*)d_in[5];
  float* out = (float*)d_out;
  char* ws = (char*)d_ws;
  int*    counts   = (int*)(ws + WS_COUNTS);
  float*  partials = (float*)(ws + WS_PART);
  int*    ntp      = (int*)(ws + WS_NT);
  int*    off      = (int*)(ws + WS_OFF);
  int4*   entries  = (int4*)(ws + WS_ENT);
  int*    blockbase= (int*)(ws + WS_BB);
  int*    pidlr    = (int*)(ws + WS_PIDLR);
  float2* gatesb   = (float2*)(ws + WS_GATEB);
  float*  w8       = (float*)(ws + WS_W8);
  int*    rows_s   = (int*)(ws + WS_ROWSS);
  unsigned short* wt2 = (unsigned short*)(ws + WS_WT);

  hipMemsetAsync(ws, 0, 256, stream);   // counts
  cvtw2_k<<<dim3(29, 8), 256, 0, stream>>>(W, wt2);
  gating_k<<<B_ROWS/256, 256, 0, stream>>>(logits, masks, counts, partials, pidlr, gatesb, w8, blockbase);
  worklist_k<<<1, 64, 0, stream>>>(counts, partials, off, ntp, entries, out);
  selemb_k<<<B_ROWS/2, 256, 0, stream>>>(sel, w8, pidlr, off, blockbase, rows_s, out);
  gemm_k<<<4*MAXT, 256, 0, stream>>>(x, wt2, bias, ntp, entries, rows_s, gatesb, out);
}

// Round 6
// 274.025 us; speedup vs baseline: 1.1854x; 1.1854x over previous
//
#include <hip/hip_runtime.h>
#include <hip/hip_bf16.h>

// f32-uniform output buffer: final_out [B,512] (bf16-rounded f32),
// guide_loss f32 @ B*512, sel_emb [B,128] f32 @ B*512+1.
// B=16384, E=8, D_IN=900, D_MODEL=512, D_SEL=128, top-2.

#define B_ROWS 16384
#define DIN 900
#define DM 512
#define DSEL 128
#define KP 928
#define NKS 29
#define MAXT 192
#define EPSF 1e-9f

#define OUT_GUIDE (B_ROWS*DM)
#define OUT_SEL   (B_ROWS*DM + 1)

// workspace layout (bytes); total ~8.4 MB (proven footprint)
#define WS_COUNTS 0                      // (unused now)
#define WS_PART   512                    // float[64]
#define WS_NT     768                    // int
#define WS_OFF    1024                   // int[64]
#define WS_ENT    2048                   // int4[448]
#define WS_BB     9216                   // int[64*64] per-block hist -> prefix
#define WS_PIDLR  25600                  // int[B]  pid | (lrank<<8)
#define WS_GATEB  91136                  // float2[B]
#define WS_W8     222208                 // float[B*8] inactive-mixture weights
#define WS_ROWSS  746496                 // int[B]
#define WS_WT     812032                 // ushort[E*32*29*512] frag-tiled W (7.6 MB)

typedef __attribute__((ext_vector_type(8))) short short8;
typedef __attribute__((ext_vector_type(8))) unsigned short ushort8;
typedef __attribute__((ext_vector_type(4))) float floatx4;

__device__ inline unsigned short f2bf(float v){
  union { __hip_bfloat16 h; unsigned short u; } c;
  c.h = __float2bfloat16(v);
  return c.u;
}
__device__ inline float bf2f(unsigned short u){
  union { unsigned int i; float f; } c;
  c.i = ((unsigned int)u) << 16;
  return c.f;
}
__device__ inline ushort8 pack8u(float4 a, float4 b){
  ushort8 c;
  c[0]=f2bf(a.x); c[1]=f2bf(a.y); c[2]=f2bf(a.z); c[3]=f2bf(a.w);
  c[4]=f2bf(b.x); c[5]=f2bf(b.y); c[6]=f2bf(b.z); c[7]=f2bf(b.w);
  return c;
}

// ---- fused prep: blocks [0,232) = W conversion; blocks [232,296) = gating ----
// cvtw2 role: W f32 [E,900,512] -> bf16 frag tiles wt2[e][ncg][kc][col16][kk32]
// gating role: per-row softmax/top2; per-block hist -> blockbase (NO global atomics)
__global__ __launch_bounds__(256) void prep_k(const float* __restrict__ W,
                                              unsigned short* __restrict__ wt2,
                                              const float* __restrict__ logits,
                                              const int* __restrict__ masks,
                                              float* __restrict__ partials,
                                              int* __restrict__ pidlr,
                                              float2* __restrict__ gatesb,
                                              float* __restrict__ w8,
                                              int* __restrict__ blockbase){
  __shared__ unsigned short lds[32][512];
  __shared__ int hist[64];
  __shared__ float wsum[4];
  int t = threadIdx.x;
  int bid = blockIdx.x;
  if (bid < 232){
    // ---- cvtw2 role ----
    int kc = bid % 29, e = bid / 29;
    for (int kk = 0; kk < 32; ++kk){
      int k = kc*32 + kk;
      if (k < DIN){
        const float* wr = W + ((size_t)e*DIN + k)*DM;
        lds[kk][t]       = f2bf(wr[t]);
        lds[kk][t + 256] = f2bf(wr[t + 256]);
      } else {
        lds[kk][t] = 0; lds[kk][t + 256] = 0;
      }
    }
    __syncthreads();
    int ncg = t >> 3, q = t & 7;
    unsigned short* ob = wt2 + (((size_t)e*32 + ncg)*29 + kc)*512;
    for (int i = 0; i < 8; ++i){
      int fb = i*64 + q*8;
      int col = fb >> 5, kk0 = fb & 31;
      ushort8 y;
      #pragma unroll
      for (int j = 0; j < 8; ++j) y[j] = lds[kk0 + j][ncg*16 + col];
      *((ushort8*)(ob + fb)) = y;
    }
    return;
  }
  // ---- gating role ----
  int gb = bid - 232;
  if (t < 64) hist[t] = 0;
  __syncthreads();
  int b = gb*256 + t;
  float4 l0 = *(const float4*)&logits[(size_t)b*8];
  float4 l1 = *(const float4*)&logits[(size_t)b*8 + 4];
  int4  m0 = *(const int4*)&masks[(size_t)b*8];
  int4  m1 = *(const int4*)&masks[(size_t)b*8 + 4];
  float raw[8] = {l0.x,l0.y,l0.z,l0.w,l1.x,l1.y,l1.z,l1.w};
  int   mk[8]  = {m0.x,m0.y,m0.z,m0.w,m1.x,m1.y,m1.z,m1.w};
  float mx = raw[0];
  for (int e = 1; e < 8; e++) mx = fmaxf(mx, raw[e]);
  float Z = 0.f;
  for (int e = 0; e < 8; e++){ raw[e] = expf(raw[e]-mx); Z += raw[e]; }
  float invZ = 1.f/Z;
  float act[8], ina[8]; float srm = 0.f, isum = 0.f;
  for (int e = 0; e < 8; e++){
    raw[e] *= invZ;
    if (mk[e] == 1){ act[e] = raw[e]; ina[e] = 0.f; srm += raw[e]; }
    else           { act[e] = 0.f;    ina[e] = raw[e]; isum += raw[e]; }
  }
  float v1 = -1.f, v2 = -1.f; int e1 = 0, e2 = 0;
  for (int e = 0; e < 8; e++){
    float a = act[e];
    if (a > v1){ v2 = v1; e2 = e1; v1 = a; e1 = e; }
    else if (a > v2){ v2 = a; e2 = e; }
  }
  float den = v1 + v2 + EPSF;
  float g1 = v1/den, g2 = v2/den;
  int lo, hi; float gl, gh;
  if (e1 < e2){ lo = e1; hi = e2; gl = g1; gh = g2; }
  else        { lo = e2; hi = e1; gl = g2; gh = g1; }
  int pid = lo*8 + hi;
  float invI = 1.f/(isum + EPSF);
  for (int e = 0; e < 8; e++) w8[(size_t)b*8 + e] = ina[e]*invI;
  gatesb[b] = make_float2(gl, gh);
  int lr = atomicAdd(&hist[pid], 1);     // LDS atomic: local rank
  pidlr[b] = pid | (lr << 8);
  float s = srm;
  for (int sft = 32; sft > 0; sft >>= 1) s += __shfl_down(s, sft, 64);
  if ((t & 63) == 0) wsum[t >> 6] = s;
  __syncthreads();
  if (t < 64) blockbase[gb*64 + t] = hist[t];      // raw hist; prefixed by worklist
  if (t == 0) partials[gb] = wsum[0] + wsum[1] + wsum[2] + wsum[3];
}

// ---- worklist: one 64-lane wave; in-place prefix of blockbase; guide loss ----
__global__ void worklist_k(int* __restrict__ blockbase,
                           const float* __restrict__ partials,
                           int* __restrict__ off, int* __restrict__ ntp,
                           int4* __restrict__ entries,
                           float* __restrict__ out){
  int lane = threadIdx.x;      // 64 threads; lane = pid
  // exclusive prefix over the 64 gating blocks for this pid (batched loads)
  int s = 0;
  for (int b0 = 0; b0 < 64; b0 += 16){
    int v[16];
    #pragma unroll
    for (int j = 0; j < 16; ++j) v[j] = blockbase[(b0+j)*64 + lane];
    #pragma unroll
    for (int j = 0; j < 16; ++j){ blockbase[(b0+j)*64 + lane] = s; s += v[j]; }
  }
  int c = s;                   // total rows for this pid
  int sc = c;
  for (int sh = 1; sh < 64; sh <<= 1){ int v = __shfl_up(sc, sh, 64); if (lane >= sh) sc += v; }
  int offp = sc - c;
  off[lane] = offp;
  int nt = (c + 127) >> 7;
  int snt = nt;
  for (int sh = 1; sh < 64; sh <<= 1){ int v = __shfl_up(snt, sh, 64); if (lane >= sh) snt += v; }
  int tbase = snt - nt;
  int elo = lane >> 3, ehi = lane & 7;
  for (int j = 0; j < nt; ++j){
    int nr = c - j*128; if (nr > 128) nr = 128;
    entries[tbase + j] = make_int4(elo, ehi, offp + j*128, nr);
  }
  int tot = __shfl(snt, 63, 64);
  if (lane == 0) *ntp = tot;
  float p = partials[lane];
  for (int sh = 32; sh > 0; sh >>= 1) p += __shfl_down(p, sh, 64);
  if (lane == 0){
    float sv = p * (1.f/B_ROWS);
    float d = 1.f - sv;
    out[OUT_GUIDE] = d*d;
  }
}

// ---- selection embedding (+ fused scatter): coalesced, 2 rows per block ----
__global__ __launch_bounds__(256) void selemb_k(const float* __restrict__ sel,
                                                const float* __restrict__ w8,
                                                const int* __restrict__ pidlr,
                                                const int* __restrict__ off,
                                                const int* __restrict__ blockbase,
                                                int* __restrict__ rows_s,
                                                float* __restrict__ out){
  int t = threadIdx.x;
  int b = blockIdx.x*2 + (t >> 7);
  int d = t & 127;
  if (d == 0){
    int pl = pidlr[b];
    int p = pl & 63;
    int lr = pl >> 8;
    rows_s[off[p] + blockbase[(b >> 8)*64 + p] + lr] = b;
  }
  const float* wr = w8 + (size_t)b*8;
  const float* sb = sel + (size_t)b*(8*DSEL);
  float a = 0.f;
  for (int e = 0; e < 8; e++) a += wr[e] * sb[e*DSEL + d];
  out[OUT_SEL + (size_t)b*DSEL + d] = a;
}

// ---- grouped GEMM v6: R4 multicast structure + proven fixes.
//      A staged in LDS pad-36 (bank-uniform), depth-2 register prefetch;
//      B staged in LDS [grp][quad][col16] (bank-uniform writes AND reads),
//      depth-1 register prefetch; dbuf, ONE barrier per K-step;
//      XCD swizzle co-locates a tile's 4 col-blocks on one XCD. ----

#define ALOADV(P, kk) { \
  const float4* p_ = (const float4*)(xrow + (kk)*32); \
  P##0 = p_[0]; P##1 = p_[1]; P##2 = p_[2]; P##3 = p_[3]; }

#define ALOADT(P) { \
  float tmp[16]; \
  _Pragma("unroll") \
  for (int j = 0; j < 16; ++j){ \
    int k = 896 + skc*16 + j; \
    tmp[j] = (k < DIN) ? xrow[28*32 + j] : 0.f; \
  } \
  P##0 = make_float4(tmp[0],tmp[1],tmp[2],tmp[3]); \
  P##1 = make_float4(tmp[4],tmp[5],tmp[6],tmp[7]); \
  P##2 = make_float4(tmp[8],tmp[9],tmp[10],tmp[11]); \
  P##3 = make_float4(tmp[12],tmp[13],tmp[14],tmp[15]); }

#define AWR(buf, P) { \
  *((ushort8*)&as_[buf][srow*36 + skc*16])     = pack8u(P##0, P##1); \
  *((ushort8*)&as_[buf][srow*36 + skc*16 + 8]) = pack8u(P##2, P##3); }

#define BLOADG(kk) { \
  bw0 = *((const ushort8*)(bgp0 + (size_t)(kk)*512)); \
  bw1 = *((const ushort8*)(bgp1 + (size_t)(kk)*512)); \
  bw2 = *((const ushort8*)(bgp2 + (size_t)(kk)*512)); \
  bw3 = *((const ushort8*)(bgp3 + (size_t)(kk)*512)); }

#define BWR(buf) { \
  *((ushort8*)&bs_[buf][bo0]) = bw0; \
  *((ushort8*)&bs_[buf][bo1]) = bw1; \
  *((ushort8*)&bs_[buf][bo2]) = bw2; \
  *((ushort8*)&bs_[buf][bo3]) = bw3; }

#define KSTEP(cur) { \
  short8 af0 = *((const short8*)&as_[cur][(wrow*64 +  0 + l16)*36 + quad*8]); \
  short8 af1 = *((const short8*)&as_[cur][(wrow*64 + 16 + l16)*36 + quad*8]); \
  short8 af2 = *((const short8*)&as_[cur][(wrow*64 + 32 + l16)*36 + quad*8]); \
  short8 af3 = *((const short8*)&as_[cur][(wrow*64 + 48 + l16)*36 + quad*8]); \
  _Pragma("unroll") \
  for (int e = 0; e < 2; ++e){ \
    _Pragma("unroll") \
    for (int nt = 0; nt < 4; ++nt){ \
      short8 bfr = *((const short8*)&bs_[cur][(e*8 + wcol*4 + nt)*512 + quad*128 + l16*8]); \
      acc[e][0][nt] = __builtin_amdgcn_mfma_f32_16x16x32_bf16(af0, bfr, acc[e][0][nt], 0, 0, 0); \
      acc[e][1][nt] = __builtin_amdgcn_mfma_f32_16x16x32_bf16(af1, bfr, acc[e][1][nt], 0, 0, 0); \
      acc[e][2][nt] = __builtin_amdgcn_mfma_f32_16x16x32_bf16(af2, bfr, acc[e][2][nt], 0, 0, 0); \
      acc[e][3][nt] = __builtin_amdgcn_mfma_f32_16x16x32_bf16(af3, bfr, acc[e][3][nt], 0, 0, 0); \
    } \
  } }

__global__ __launch_bounds__(256, 2) void gemm_k(const float* __restrict__ xf,
                                                 const unsigned short* __restrict__ wt2,
                                                 const float* __restrict__ bias,
                                                 const int* __restrict__ ntp,
                                                 const int4* __restrict__ entries,
                                                 const int* __restrict__ rows_s,
                                                 const float2* __restrict__ gatesb,
                                                 float* __restrict__ out){
  // XCD swizzle: the 4 col-blocks of a tile share id%8 -> same XCD
  int id = blockIdx.x;
  int tile = (id >> 5)*8 + (id & 7);
  int y = (id >> 3) & 3;
  if (tile >= *ntp) return;
  int4 ent = entries[tile];
  int elo = ent.x, ehi = ent.y, start = ent.z, nrows = ent.w;

  __shared__ __align__(16) unsigned short as_[2][128*36];   // A bf16, 72B rows
  __shared__ __align__(16) unsigned short bs_[2][16*512];   // B [grp][quad128][col8]
  __shared__ int   gidx_s[128];
  __shared__ float glo_s[128];
  __shared__ float ghi_s[128];

  int t = threadIdx.x;
  if (t < 128){
    if (t < nrows){
      int g = rows_s[start + t];
      gidx_s[t] = g;
      float2 gg = gatesb[g];
      glo_s[t] = gg.x; ghi_s[t] = gg.y;
    } else { gidx_s[t] = -1; glo_s[t] = 0.f; ghi_s[t] = 0.f; }
  }
  __syncthreads();

  int lane = t & 63, wid = t >> 6;
  int wrow = wid >> 1, wcol = wid & 1;
  int quad = lane >> 4, l16 = lane & 15;

  // A staging: thread t stages row t>>1, half (t&1)*16 of each 32-k chunk
  int srow = t >> 1, skc = t & 1;
  int sg = gidx_s[srow];
  const float* xrow = xf + (size_t)(sg >= 0 ? sg : 0)*DIN + skc*16;

  // B staging: 4 units/thread; unit u=i*256+t -> grp=u>>6 (0..15), v=u&63
  //   global: frag tile (e(grp), y*8+(grp&7)) at 16B-unit v; LDS: [grp][v&3][v>>2]
  const unsigned short *bgp0, *bgp1, *bgp2, *bgp3;
  int bo0, bo1, bo2, bo3;
  {
    int v = t & 63;
    int goff = v*8;
    int lofs = (v & 3)*128 + (v >> 2)*8;
    int g0 = t >> 6, g1 = (256+t) >> 6, g2 = (512+t) >> 6, g3 = (768+t) >> 6;
    bgp0 = wt2 + ((size_t)((g0 < 8 ? elo : ehi)*32 + y*8 + (g0 & 7))*29)*512 + goff;
    bgp1 = wt2 + ((size_t)((g1 < 8 ? elo : ehi)*32 + y*8 + (g1 & 7))*29)*512 + goff;
    bgp2 = wt2 + ((size_t)((g2 < 8 ? elo : ehi)*32 + y*8 + (g2 & 7))*29)*512 + goff;
    bgp3 = wt2 + ((size_t)((g3 < 8 ? elo : ehi)*32 + y*8 + (g3 & 7))*29)*512 + goff;
    bo0 = g0*512 + lofs; bo1 = g1*512 + lofs; bo2 = g2*512 + lofs; bo3 = g3*512 + lofs;
  }

  floatx4 acc[2][4][4];
  #pragma unroll
  for (int i = 0; i < 2; i++)
    #pragma unroll
    for (int j = 0; j < 4; j++)
      #pragma unroll
      for (int k = 0; k < 4; k++)
        #pragma unroll
        for (int r = 0; r < 4; r++) acc[i][j][k][r] = 0.f;

  float4 rE0, rE1, rE2, rE3;   // A raw regs, even steps (depth-2)
  float4 rO0, rO1, rO2, rO3;   // A raw regs, odd steps
  ushort8 bw0, bw1, bw2, bw3;  // B regs (depth-1)

  ALOADV(rE, 0);
  ALOADV(rO, 1);
  BLOADG(0);
  AWR(0, rE); BWR(0);
  __syncthreads();

  for (int ks = 0; ks < 28; ks += 2){
    // even: compute ks (buf0); issue A(ks+2), B(ks+1); write buf1 <- A(ks+1),B(ks+1)
    if (ks < 26){ ALOADV(rE, ks+2); } else { ALOADT(rE); }
    BLOADG(ks+1);
    KSTEP(0);
    AWR(1, rO); BWR(1);
    __syncthreads();
    // odd: compute ks+1 (buf1); issue A(ks+3), B(ks+2); write buf0 <- A(ks+2),B(ks+2)
    if (ks < 26){ ALOADV(rO, ks+3); }
    BLOADG(ks+2);
    KSTEP(1);
    AWR(0, rE); BWR(0);
    __syncthreads();
  }
  KSTEP(0);   // K-step 28

  // epilogue: gates + bias in f32 (== ref's g*(xW+b) summed over top-2)
  int colbase = y*128 + wcol*64;
  float blo[4], bhi[4];
  #pragma unroll
  for (int nt = 0; nt < 4; ++nt){
    int n = colbase + nt*16 + l16;
    blo[nt] = bias[elo*DM + n];
    bhi[nt] = bias[ehi*DM + n];
  }
  #pragma unroll
  for (int mt = 0; mt < 4; ++mt){
    #pragma unroll
    for (int r = 0; r < 4; ++r){
      int rr = wrow*64 + mt*16 + quad*4 + r;
      int grow = gidx_s[rr];
      if (grow >= 0){
        float2 gg = gatesb[grow];
        float* orow = out + (size_t)grow*DM;
        #pragma unroll
        for (int nt = 0; nt < 4; ++nt){
          int n = colbase + nt*16 + l16;
          float v = gg.x*(acc[0][mt][nt][r] + blo[nt]) + gg.y*(acc[1][mt][nt][r] + bhi[nt]);
          orow[n] = bf2f(f2bf(v));
        }
      }
    }
  }
}

extern "C" void kernel_launch(void* const* d_in, const int* in_sizes, int n_in,
                              void* d_out, int out_size, void* d_ws, size_t ws_size,
                              hipStream_t stream){
  const float* x      = (const float*)d_in[0];
  const float* logits = (const float*)d_in[1];
  const int*   masks  = (const int*)d_in[2];
  const float* sel    = (const float*)d_in[3];
  const float* W      = (const float*)d_in[4];
  const float* bias   = (const float*)d_in[5];
  float* out = (float*)d_out;
  char* ws = (char*)d_ws;
  float*  partials = (float*)(ws + WS_PART);
  int*    ntp      = (int*)(ws + WS_NT);
  int*    off      = (int*)(ws + WS_OFF);
  int4*   entries  = (int4*)(ws + WS_ENT);
  int*    blockbase= (int*)(ws + WS_BB);
  int*    pidlr    = (int*)(ws + WS_PIDLR);
  float2* gatesb   = (float2*)(ws + WS_GATEB);
  float*  w8       = (float*)(ws + WS_W8);
  int*    rows_s   = (int*)(ws + WS_ROWSS);
  unsigned short* wt2 = (unsigned short*)(ws + WS_WT);

  // 4 dispatches total (was 7): prep(cvtw2+gating) -> worklist -> selemb -> gemm
  prep_k<<<296, 256, 0, stream>>>(W, wt2, logits, masks, partials, pidlr, gatesb, w8, blockbase);
  worklist_k<<<1, 64, 0, stream>>>(blockbase, partials, off, ntp, entries, out);
  selemb_k<<<B_ROWS/2, 256, 0, stream>>>(sel, w8, pidlr, off, blockbase, rows_s, out);
  gemm_k<<<4*MAXT, 256, 0, stream>>>(x, wt2, bias, ntp, entries, rows_s, gatesb, out);
}